// Round 17
// baseline (673.244 us; speedup 1.0000x reference)
//
#include <hip/hip_runtime.h>
#include <cstdint>
#include <cstddef>

// Problem constants
#define BB 8
#define SS 1024
#define DDIM 512
#define HH 8
#define BS 8192   // BB*SS
#define HD 4096   // HH*DDIM

typedef __attribute__((ext_vector_type(4))) float f32x4;
typedef __attribute__((ext_vector_type(8))) short bf16x8;    // 8 bf16 (4 VGPRs) — MFMA A/B frag
typedef __attribute__((ext_vector_type(4))) unsigned short u16x4;

// ---- helpers -------------------------------------------------------------

__device__ __forceinline__ unsigned short f2bf(float f) {
  union { float f; unsigned int u; } x; x.f = f;
  unsigned int r = x.u + 0x7fffu + ((x.u >> 16) & 1u);   // RNE
  return (unsigned short)(r >> 16);
}

// async global->LDS, 16B per lane. LDS dest is wave-uniform base + lane*16.
__device__ __forceinline__ void gload16(const void* g, void* l) {
  __builtin_amdgcn_global_load_lds(
      (const __attribute__((address_space(1))) unsigned int*)g,
      (__attribute__((address_space(3))) unsigned int*)l, 16, 0, 0);
}

// raw barrier + LDS drain (never drains vmcnt -> staging stays in flight)
#define BAR_LGKM() do { asm volatile("s_waitcnt lgkmcnt(0)" ::: "memory"); \
                        __builtin_amdgcn_s_barrier(); } while (0)
// full drain barrier (staged tile ready)
#define BAR_ALL()  do { asm volatile("s_waitcnt vmcnt(0) lgkmcnt(0)" ::: "memory"); \
                        __builtin_amdgcn_s_barrier(); } while (0)

// ---- conversion / transpose kernels -------------------------------------

__global__ void k_convert(const float* __restrict__ in, unsigned short* __restrict__ out, int n4) {
  int i = blockIdx.x * blockDim.x + threadIdx.x;
  if (i < n4) {
    float4 v = ((const float4*)in)[i];
    u16x4 o;
    o[0] = f2bf(v.x); o[1] = f2bf(v.y); o[2] = f2bf(v.z); o[3] = f2bf(v.w);
    ((u16x4*)out)[i] = o;
  }
}

// in: f32 [z][R][C] -> out: bf16 [z][C][R]
__global__ void k_transpose_f2b(const float* __restrict__ in, unsigned short* __restrict__ out,
                                int R, int C) {
  __shared__ unsigned short tile[64][65];
  const int z = blockIdx.z;
  const int r0 = blockIdx.x << 6, c0 = blockIdx.y << 6;
  const float* ip = in + (size_t)z * R * C;
  unsigned short* op = out + (size_t)z * R * C;
  const int t = threadIdx.x;
#pragma unroll
  for (int i = 0; i < 16; ++i) {
    int idx = t + (i << 8); int r = idx >> 6, c = idx & 63;
    tile[r][c] = f2bf(ip[(size_t)(r0 + r) * C + (c0 + c)]);
  }
  __syncthreads();
#pragma unroll
  for (int i = 0; i < 16; ++i) {
    int idx = t + (i << 8); int c = idx >> 6, r = idx & 63;
    op[(size_t)(c0 + c) * R + (r0 + r)] = tile[r][c];
  }
}

// ---- GEMM core: 128x128 tile, BK=64, 4 waves, gload_lds + XOR swizzle ----
template<int A_RS, int B_RS, int KITERS>
__device__ __forceinline__ void gemm_core(const char* Ag, const char* Bg,
                                          char* As, char* Bs, f32x4 acc[4][4]) {
  const int tid = threadIdx.x;
  const int wave = tid >> 6, lane = tid & 63;
  const int wr = (wave >> 1) << 6, wc = (wave & 1) << 6;
  const int srow = (wave << 3) + (lane >> 3);                       // 0..31
  const int scol = ((lane & 7) << 4) ^ ((lane >> 3) << 4);          // pre-swizzled source col byte

  for (int kb = 0; kb < KITERS; ++kb) {
    __syncthreads();
#pragma unroll
    for (int j = 0; j < 4; ++j) {
      gload16(Ag + (size_t)(j * 32 + srow) * A_RS + (size_t)kb * 128 + scol,
              As + j * 4096 + wave * 1024);
      gload16(Bg + (size_t)(j * 32 + srow) * B_RS + (size_t)kb * 128 + scol,
              Bs + j * 4096 + wave * 1024);
    }
    asm volatile("s_waitcnt vmcnt(0)" ::: "memory");
    __syncthreads();
#pragma unroll
    for (int ks = 0; ks < 2; ++ks) {
      bf16x8 af[4], bfr[4];
      const int kcol = (ks << 6) + ((lane >> 4) << 4);
#pragma unroll
      for (int i = 0; i < 4; ++i) {
        const int ar = wr + (i << 4) + (lane & 15);
        af[i] = *(const bf16x8*)(As + ar * 128 + (kcol ^ ((ar & 7) << 4)));
        const int br = wc + (i << 4) + (lane & 15);
        bfr[i] = *(const bf16x8*)(Bs + br * 128 + (kcol ^ ((br & 7) << 4)));
      }
#pragma unroll
      for (int i = 0; i < 4; ++i)
#pragma unroll
        for (int j = 0; j < 4; ++j)
          acc[i][j] = __builtin_amdgcn_mfma_f32_16x16x32_bf16(af[i], bfr[j], acc[i][j], 0, 0, 0);
    }
  }
}

// ---- QKV projection (phase of 2 batches), XCD-pinned 1-D grid -------------
__global__ __launch_bounds__(256, 2) void k_gemm_qkv(
    const unsigned short* __restrict__ xbf,
    const unsigned short* __restrict__ wqT, const unsigned short* __restrict__ wkT,
    const unsigned short* __restrict__ wvT,
    const float* __restrict__ bq, const float* __restrict__ bk, const float* __restrict__ bv,
    unsigned short* __restrict__ Qo, unsigned short* __restrict__ Ko,
    unsigned short* __restrict__ VTo, int b0) {
  __shared__ __align__(16) char As[16384], Bs[16384];
  const int idx = blockIdx.x;
  const int xcd = idx & 7;
  const int q = idx >> 3;                   // 0..191
  const int m0 = (q & 15) << 7;             // 16 m-panels over 2048 rows
  const int zn = ((q >> 4) << 3) + xcd;     // 0..95
  const int z = zn >> 2;
  const int n0 = (zn & 3) << 7;
  const int p = z >> 3, h = z & 7;
  const unsigned short* wT = (p == 0) ? wqT : (p == 1) ? wkT : wvT;
  const float* bias = ((p == 0) ? bq : (p == 1) ? bk : bv) + (h << 9);
  const char* Ag = (const char*)xbf + ((size_t)(b0 << 10) + m0) * 1024;
  const char* Bg = (const char*)wT + (size_t)h * 524288 + (size_t)n0 * 1024;
  f32x4 acc[4][4] = {};
  gemm_core<1024, 1024, 8>(Ag, Bg, As, Bs, acc);

  const int tid = threadIdx.x, wave = tid >> 6, lane = tid & 63;
  const int wr = (wave >> 1) << 6, wc = (wave & 1) << 6;
  if (p == 2) {
#pragma unroll
    for (int j = 0; j < 4; ++j) {
      const int col = n0 + wc + (j << 4) + (lane & 15);
      const float bb = bias[col];
#pragma unroll
      for (int i = 0; i < 4; ++i) {
        const int sb = m0 + wr + (i << 4) + ((lane >> 4) << 2);   // 4 consecutive s rows
        const int lb = sb >> 10, s = sb & 1023;
        u16x4 o;
#pragma unroll
        for (int r = 0; r < 4; ++r) o[r] = f2bf(acc[i][j][r] + bb);
        *(u16x4*)(VTo + (size_t)(lb * HH + h) * 524288 +
                  (size_t)(((s >> 5) << 9) + col) * 32 + (s & 31)) = o;
      }
    }
  } else {
    unsigned short* dst = (p == 0) ? Qo : Ko;
#pragma unroll
    for (int j = 0; j < 4; ++j) {
      const int col = n0 + wc + (j << 4) + (lane & 15);
      const float bb = bias[col];
#pragma unroll
      for (int i = 0; i < 4; ++i)
#pragma unroll
        for (int r = 0; r < 4; ++r) {
          const int m = m0 + wr + (i << 4) + ((lane >> 4) << 2) + r;
          const int lb = m >> 10, s = m & 1023;
          dst[((size_t)((lb * HH + h) * SS + s) << 9) + col] = f2bf(acc[i][j][r] + bb);
        }
    }
  }
}

// ---- output projection, XCD-pinned 1-D grid 256 ---------------------------
__global__ __launch_bounds__(256, 2) void k_gemm_out(
    const unsigned short* __restrict__ concat, const unsigned short* __restrict__ woT,
    const float* __restrict__ bo, float* __restrict__ out) {
  __shared__ __align__(16) char As[16384], Bs[16384];
  const int idx = blockIdx.x;
  const int xcd = idx & 7;
  const int n0 = (xcd & 3) << 7;
  const int m0 = ((idx >> 3) + ((xcd >> 2) << 5)) << 7;
  const char* Ag = (const char*)concat + (size_t)m0 * 8192;
  const char* Bg = (const char*)woT + (size_t)n0 * 8192;
  f32x4 acc[4][4] = {};
  gemm_core<8192, 8192, 64>(Ag, Bg, As, Bs, acc);

  const int tid = threadIdx.x, wave = tid >> 6, lane = tid & 63;
  const int wr = (wave >> 1) << 6, wc = (wave & 1) << 6;
#pragma unroll
  for (int j = 0; j < 4; ++j) {
    const int col = n0 + wc + (j << 4) + (lane & 15);
    const float bb = bo[col];
#pragma unroll
    for (int i = 0; i < 4; ++i)
#pragma unroll
      for (int r = 0; r < 4; ++r) {
        const int m = m0 + wr + (i << 4) + ((lane >> 4) << 2) + r;
        out[(size_t)m * DDIM + col] = acc[i][j][r] + bb;
      }
  }
}

// ---- flash attention v12: v11 + in-register softmax (S round-trip killed) -
// After QK^T each wave holds its 16x16 S-frag in regs (rows qi*16+(lane>>4)*4
// +r, col ni*16+l15). Row max/sum over 16 cols = 4 shfl_xor steps within
// 16-lane groups; only the ni-half combine goes through LDS (pmax/psum
// [2][64] f32). exp in-register, P written straight from the fragment.
// Defer-max (T13) kept. Barriers/iter unchanged (3) + 1 after loop for lsm.
// LDS 138048: K dbuf 64KB | V dbuf 64KB | P [64x80B] | m/l/f[64] |
//             pmax[2][64] | psum[2][64] | wfl[8]
__global__ __launch_bounds__(512, 1) void k_attn(
    const unsigned short* __restrict__ Qg, const unsigned short* __restrict__ Kg,
    const unsigned short* __restrict__ VT2g, unsigned short* __restrict__ Og,
    int b0) {
  __shared__ __align__(16) char smem[138048];
  char*  Psm = smem + 131072;                // 64*80 = 5120
  float* msm = (float*)(smem + 136192);
  float* lsm = (float*)(smem + 136448);
  float* fsm = (float*)(smem + 136704);
  float* pmx = (float*)(smem + 136960);      // [2][64]
  float* psu = (float*)(smem + 137472);      // [2][64]
  float* wfl = (float*)(smem + 137984);      // [8]

  const int tid = threadIdx.x, wave = tid >> 6, lane = tid & 63;
  const int bh = blockIdx.x & 15;            // local bh; bh&7 = head = XCD pin
  const int qt = blockIdx.x >> 4;            // 16 qtiles of 64 rows
  const int q0 = qt << 6;
  const char* Qb = (const char*)Qg + (size_t)bh * 1048576;     // SS*DDIM*2
  const char* Kb = (const char*)Kg + (size_t)bh * 1048576;
  const char* Vb = (const char*)VT2g + (size_t)bh * 1048576;   // [32][512][32] tiled

  const int qi = wave >> 1, ni = wave & 1;   // QK^T: 4 qfrag x 2 nfrag
  const int l15 = lane & 15;
  const int kg16 = (lane >> 4) << 4;
  const int rowb = (qi << 4) + ((lane >> 4) << 2);   // frag row base for this lane

  if (tid < 64) { msm[tid] = -1e30f; lsm[tid] = 0.0f; }

  // K tile: 32 rows x 1KB. V tile: contiguous 32KB [512 d][32 kv], swizzled.
#define STAGE_K(KV0, BUF)                                                      \
  {                                                                            \
    _Pragma("unroll")                                                          \
    for (int j = 0; j < 4; ++j) {                                              \
      const int row = (j << 3) + wave;                                         \
      gload16(Kb + (size_t)((KV0) + row) * 1024 + ((lane << 4) ^ ((row & 7) << 4)), \
              smem + (BUF) * 32768 + row * 1024);                              \
    }                                                                          \
  }
#define STAGE_V(KT, BUF)                                                       \
  {                                                                            \
    const char* vsrc = Vb + (size_t)(KT) * 32768;                              \
    _Pragma("unroll")                                                          \
    for (int j = 0; j < 4; ++j) {                                              \
      const int idx = (j << 3) + wave;                                         \
      gload16(vsrc + idx * 1024 + (size_t)((lane >> 2) << 6) +                 \
                  ((((lane & 3) ^ ((lane >> 3) & 3))) << 4),                   \
              smem + 65536 + (BUF) * 32768 + idx * 1024);                      \
    }                                                                          \
  }

  // ---- prologue: Q fragments direct to regs (one-time); stage tile 0 ----
  bf16x8 qf[16];
  {
    const char* qrow = Qb + (size_t)(q0 + (qi << 4) + l15) * 1024 + kg16;
#pragma unroll
    for (int ks = 0; ks < 16; ++ks)
      qf[ks] = *(const bf16x8*)(qrow + (ks << 6));
  }
  STAGE_K(0, 0);
  STAGE_V(0, 0);

  f32x4 accO[4][4] = {};
  const float scale = 0.044194173824159216f;   // 1/sqrt(512)

  for (int kt = 0; kt < 32; ++kt) {            // 32 tiles x kv=32 = SS=1024
    const int cur = kt & 1;
    BAR_ALL();   // staged K/V(kt) landed; all waves done reading buf[cur^1]
    if (kt != 31) {
      STAGE_K((kt + 1) << 5, cur ^ 1);   // full-iteration prefetch distance
      STAGE_V(kt + 1, cur ^ 1);
    }

    // ---- QK^T: one 16x16 S-frag per wave, 4 independent MFMA chains ----
    f32x4 s;
    {
      f32x4 a0 = {}, a1 = {}, a2 = {}, a3 = {};
      const int krow = (ni << 4) + l15;
      const char* kb2 = smem + cur * 32768 + krow * 1024;
      const int ksz = (krow & 7) << 4;
      __builtin_amdgcn_s_setprio(1);
#pragma unroll
      for (int ks = 0; ks < 16; ks += 4) {
        const bf16x8 k0 = *(const bf16x8*)(kb2 + ((((ks + 0) << 6) + kg16) ^ ksz));
        const bf16x8 k1 = *(const bf16x8*)(kb2 + ((((ks + 1) << 6) + kg16) ^ ksz));
        const bf16x8 k2 = *(const bf16x8*)(kb2 + ((((ks + 2) << 6) + kg16) ^ ksz));
        const bf16x8 k3 = *(const bf16x8*)(kb2 + ((((ks + 3) << 6) + kg16) ^ ksz));
        a0 = __builtin_amdgcn_mfma_f32_16x16x32_bf16(qf[ks + 0], k0, a0, 0, 0, 0);
        a1 = __builtin_amdgcn_mfma_f32_16x16x32_bf16(qf[ks + 1], k1, a1, 0, 0, 0);
        a2 = __builtin_amdgcn_mfma_f32_16x16x32_bf16(qf[ks + 2], k2, a2, 0, 0, 0);
        a3 = __builtin_amdgcn_mfma_f32_16x16x32_bf16(qf[ks + 3], k3, a3, 0, 0, 0);
      }
      __builtin_amdgcn_s_setprio(0);
      s = (a0 + a1) + (a2 + a3);
    }
#pragma unroll
    for (int r = 0; r < 4; ++r) s[r] *= scale;

    // ---- in-register partial row-max over this ni-half (16 cols) ----
    {
      f32x4 m4 = s;
#pragma unroll
      for (int off = 1; off < 16; off <<= 1) {
#pragma unroll
        for (int r = 0; r < 4; ++r) m4[r] = fmaxf(m4[r], __shfl_xor(m4[r], off));
      }
      if (l15 == 0) {
#pragma unroll
        for (int r = 0; r < 4; ++r) pmx[(ni << 6) + rowb + r] = m4[r];
      }
    }
    BAR_LGKM();   // pmax partials visible

    // ---- combine halves, defer-max, exp in registers, partial sums ----
    {
      f32x4 p;
      float mn[4], fc[4];
      bool any = false;
#pragma unroll
      for (int r = 0; r < 4; ++r) {
        const int row = rowb + r;
        const float mx = fmaxf(pmx[row], pmx[64 + row]);
        const float mold = msm[row];
        mn[r] = (mx - mold > 8.0f) ? mx : mold;       // T13 defer-max
        fc[r] = (mn[r] == mold) ? 1.0f : __expf(mold - mn[r]);
        p[r] = __expf(s[r] - mn[r]);
        any = any || (fc[r] != 1.0f);
      }
      f32x4 ps = p;
#pragma unroll
      for (int off = 1; off < 16; off <<= 1) {
#pragma unroll
        for (int r = 0; r < 4; ++r) ps[r] += __shfl_xor(ps[r], off);
      }
      if (l15 == 0) {
#pragma unroll
        for (int r = 0; r < 4; ++r) psu[(ni << 6) + rowb + r] = ps[r];
      }
      if (ni == 0 && l15 == 0) {
#pragma unroll
        for (int r = 0; r < 4; ++r) { msm[rowb + r] = mn[r]; fsm[rowb + r] = fc[r]; }
      }
      // P write straight from the fragment: 4 scalar bf16 stores
      const int colb2 = ((ni << 4) + l15) << 1;
#pragma unroll
      for (int r = 0; r < 4; ++r)
        *(unsigned short*)(Psm + (rowb + r) * 80 + colb2) = f2bf(p[r]);
      const unsigned long long need = __ballot(any);
      if (lane == 0) wfl[wave] = need ? 1.0f : 0.0f;
    }
    BAR_LGKM();   // P, psum, msm/fsm, flags visible

    // ---- PV: wave owns d-slice [wave*64, +64); V from swizzled LDS tile ----
    {
      bf16x8 pf[4], vf[4];
      const int rb = (lane >> 4) << 2;
      const char* vb2 = smem + 65536 + cur * 32768;
      const int vswz = ((l15 >> 1) & 3) << 4;
#pragma unroll
      for (int i = 0; i < 4; ++i)
        pf[i] = *(const bf16x8*)(Psm + ((i << 4) + l15) * 80 + kg16);
#pragma unroll
      for (int j = 0; j < 4; ++j) {
        const int vr = (wave << 6) + (j << 4) + l15;
        vf[j] = *(const bf16x8*)(vb2 + vr * 64 + (kg16 ^ vswz));
      }
      // block-uniform rescale skip (flags are block-uniform -> no divergence)
      const float anyresc = wfl[0] + wfl[1] + wfl[2] + wfl[3] +
                            wfl[4] + wfl[5] + wfl[6] + wfl[7];
      if (anyresc != 0.0f) {
        float facs[4][4];
#pragma unroll
        for (int i = 0; i < 4; ++i)
#pragma unroll
          for (int r = 0; r < 4; ++r) facs[i][r] = fsm[(i << 4) + rb + r];
#pragma unroll
        for (int i = 0; i < 4; ++i)
#pragma unroll
          for (int j = 0; j < 4; ++j)
#pragma unroll
            for (int r = 0; r < 4; ++r) accO[i][j][r] *= facs[i][r];
      }
      __builtin_amdgcn_s_setprio(1);
#pragma unroll
      for (int i = 0; i < 4; ++i)
#pragma unroll
        for (int j = 0; j < 4; ++j)
          accO[i][j] = __builtin_amdgcn_mfma_f32_16x16x32_bf16(pf[i], vf[j], accO[i][j], 0, 0, 0);
      __builtin_amdgcn_s_setprio(0);
      // l update (needs both psum halves; ordered by the P-barrier above)
      if (ni == 0 && l15 == 0) {
#pragma unroll
        for (int r = 0; r < 4; ++r) {
          const int row = rowb + r;
          lsm[row] = lsm[row] * fsm[row] + psu[row] + psu[64 + row];
        }
      }
    }
  }
  BAR_LGKM();   // all lsm updates visible to epilogue

  // ---- epilogue: O /= l, write concat [b][s][h*512+d] bf16 ----
  {
    const int b = b0 + (bh >> 3), h = bh & 7;
    const int rb = (lane >> 4) << 2;
    float linv[4][4];
#pragma unroll
    for (int i = 0; i < 4; ++i)
#pragma unroll
      for (int r = 0; r < 4; ++r) linv[i][r] = 1.0f / lsm[(i << 4) + rb + r];
#pragma unroll
    for (int i = 0; i < 4; ++i)
#pragma unroll
      for (int j = 0; j < 4; ++j) {
        const int col = (wave << 6) + (j << 4) + l15;
#pragma unroll
        for (int r = 0; r < 4; ++r) {
          const int s2 = q0 + (i << 4) + rb + r;
          Og[((size_t)((b << 10) + s2)) * HD + (h << 9) + col] = f2bf(accO[i][j][r] * linv[i][r]);
        }
      }
  }
#undef STAGE_K
#undef STAGE_V
}

// ---- host launch ---------------------------------------------------------

extern "C" void kernel_launch(void* const* d_in, const int* in_sizes, int n_in,
                              void* d_out, int out_size, void* d_ws, size_t ws_size,
                              hipStream_t stream) {
  const float* x  = (const float*)d_in[0];
  const float* Wq = (const float*)d_in[1];
  const float* bq = (const float*)d_in[2];
  const float* Wk = (const float*)d_in[3];
  const float* bk = (const float*)d_in[4];
  const float* Wv = (const float*)d_in[5];
  const float* bv = (const float*)d_in[6];
  const float* Wo = (const float*)d_in[7];
  const float* bo = (const float*)d_in[8];
  float* out = (float*)d_out;
  char* ws = (char*)d_ws;

  // Layout (top = 142.6MB, proven to fit):
  unsigned short* xbf = (unsigned short*)(ws);
  unsigned short* wqT = (unsigned short*)(ws + 8388608);
  unsigned short* wkT = (unsigned short*)(ws + 12582912);
  unsigned short* wvT = (unsigned short*)(ws + 16777216);
  unsigned short* woT = (unsigned short*)(ws + 20971520);
  unsigned short* Cw  = (unsigned short*)(ws + 25165824);
  unsigned short* Qp  = (unsigned short*)(ws + 92274688);
  unsigned short* Kp  = (unsigned short*)(ws + 92274688 + 16777216ull);
  unsigned short* VTp = (unsigned short*)(ws + 92274688 + 2 * 16777216ull);

  // 1) convert x to bf16; transpose weights to [N][K] bf16
  k_convert<<<4096, 256, 0, stream>>>(x, xbf, BS * DDIM / 4);
  k_transpose_f2b<<<dim3(8, 8, 8), 256, 0, stream>>>(Wq, wqT, 512, 512);
  k_transpose_f2b<<<dim3(8, 8, 8), 256, 0, stream>>>(Wk, wkT, 512, 512);
  k_transpose_f2b<<<dim3(8, 8, 8), 256, 0, stream>>>(Wv, wvT, 512, 512);
  k_transpose_f2b<<<dim3(64, 8, 1), 256, 0, stream>>>(Wo, woT, 4096, 512);

  // 2) 4 phases of 2 batches: QKV (XCD-pinned) -> fused attention (kv=32)
  for (int b0 = 0; b0 < BB; b0 += 2) {
    k_gemm_qkv<<<dim3(1536), 256, 0, stream>>>(xbf, wqT, wkT, wvT,
                                               bq, bk, bv, Qp, Kp, VTp, b0);
    k_attn<<<dim3(256), 512, 0, stream>>>(Qp, Kp, VTp, Cw, b0);
  }

  // 3) output projection (XCD-pinned, f32 out)
  k_gemm_out<<<dim3(256), 256, 0, stream>>>(Cw, woT, bo, out);
}

// Round 18
// 566.101 us; speedup vs baseline: 1.1893x; 1.1893x over previous
//
#include <hip/hip_runtime.h>
#include <cstdint>
#include <cstddef>

// Problem constants
#define BB 8
#define SS 1024
#define DDIM 512
#define HH 8
#define BS 8192   // BB*SS
#define HD 4096   // HH*DDIM

typedef __attribute__((ext_vector_type(4))) float f32x4;
typedef __attribute__((ext_vector_type(8))) short bf16x8;    // 8 bf16 (4 VGPRs) — MFMA A/B frag
typedef __attribute__((ext_vector_type(4))) unsigned short u16x4;

// ---- helpers -------------------------------------------------------------

__device__ __forceinline__ unsigned short f2bf(float f) {
  union { float f; unsigned int u; } x; x.f = f;
  unsigned int r = x.u + 0x7fffu + ((x.u >> 16) & 1u);   // RNE
  return (unsigned short)(r >> 16);
}

// async global->LDS, 16B per lane. LDS dest is wave-uniform base + lane*16.
__device__ __forceinline__ void gload16(const void* g, void* l) {
  __builtin_amdgcn_global_load_lds(
      (const __attribute__((address_space(1))) unsigned int*)g,
      (__attribute__((address_space(3))) unsigned int*)l, 16, 0, 0);
}

// raw barrier + LDS drain (never drains vmcnt -> staging stays in flight)
#define BAR_LGKM() do { asm volatile("s_waitcnt lgkmcnt(0)" ::: "memory"); \
                        __builtin_amdgcn_s_barrier(); } while (0)
// full drain barrier (staged tile ready)
#define BAR_ALL()  do { asm volatile("s_waitcnt vmcnt(0) lgkmcnt(0)" ::: "memory"); \
                        __builtin_amdgcn_s_barrier(); } while (0)

// ---- conversion / transpose kernels -------------------------------------

__global__ void k_convert(const float* __restrict__ in, unsigned short* __restrict__ out, int n4) {
  int i = blockIdx.x * blockDim.x + threadIdx.x;
  if (i < n4) {
    float4 v = ((const float4*)in)[i];
    u16x4 o;
    o[0] = f2bf(v.x); o[1] = f2bf(v.y); o[2] = f2bf(v.z); o[3] = f2bf(v.w);
    ((u16x4*)out)[i] = o;
  }
}

// in: f32 [z][R][C] -> out: bf16 [z][C][R]
__global__ void k_transpose_f2b(const float* __restrict__ in, unsigned short* __restrict__ out,
                                int R, int C) {
  __shared__ unsigned short tile[64][65];
  const int z = blockIdx.z;
  const int r0 = blockIdx.x << 6, c0 = blockIdx.y << 6;
  const float* ip = in + (size_t)z * R * C;
  unsigned short* op = out + (size_t)z * R * C;
  const int t = threadIdx.x;
#pragma unroll
  for (int i = 0; i < 16; ++i) {
    int idx = t + (i << 8); int r = idx >> 6, c = idx & 63;
    tile[r][c] = f2bf(ip[(size_t)(r0 + r) * C + (c0 + c)]);
  }
  __syncthreads();
#pragma unroll
  for (int i = 0; i < 16; ++i) {
    int idx = t + (i << 8); int c = idx >> 6, r = idx & 63;
    op[(size_t)(c0 + c) * R + (r0 + r)] = tile[r][c];
  }
}

// ---- GEMM core: 128x128 tile, BK=64, 4 waves, gload_lds + XOR swizzle ----
template<int A_RS, int B_RS, int KITERS>
__device__ __forceinline__ void gemm_core(const char* Ag, const char* Bg,
                                          char* As, char* Bs, f32x4 acc[4][4]) {
  const int tid = threadIdx.x;
  const int wave = tid >> 6, lane = tid & 63;
  const int wr = (wave >> 1) << 6, wc = (wave & 1) << 6;
  const int srow = (wave << 3) + (lane >> 3);                       // 0..31
  const int scol = ((lane & 7) << 4) ^ ((lane >> 3) << 4);          // pre-swizzled source col byte

  for (int kb = 0; kb < KITERS; ++kb) {
    __syncthreads();
#pragma unroll
    for (int j = 0; j < 4; ++j) {
      gload16(Ag + (size_t)(j * 32 + srow) * A_RS + (size_t)kb * 128 + scol,
              As + j * 4096 + wave * 1024);
      gload16(Bg + (size_t)(j * 32 + srow) * B_RS + (size_t)kb * 128 + scol,
              Bs + j * 4096 + wave * 1024);
    }
    asm volatile("s_waitcnt vmcnt(0)" ::: "memory");
    __syncthreads();
#pragma unroll
    for (int ks = 0; ks < 2; ++ks) {
      bf16x8 af[4], bfr[4];
      const int kcol = (ks << 6) + ((lane >> 4) << 4);
#pragma unroll
      for (int i = 0; i < 4; ++i) {
        const int ar = wr + (i << 4) + (lane & 15);
        af[i] = *(const bf16x8*)(As + ar * 128 + (kcol ^ ((ar & 7) << 4)));
        const int br = wc + (i << 4) + (lane & 15);
        bfr[i] = *(const bf16x8*)(Bs + br * 128 + (kcol ^ ((br & 7) << 4)));
      }
#pragma unroll
      for (int i = 0; i < 4; ++i)
#pragma unroll
        for (int j = 0; j < 4; ++j)
          acc[i][j] = __builtin_amdgcn_mfma_f32_16x16x32_bf16(af[i], bfr[j], acc[i][j], 0, 0, 0);
    }
  }
}

// ---- QKV projection (phase of 2 batches), XCD-pinned 1-D grid -------------
__global__ __launch_bounds__(256, 2) void k_gemm_qkv(
    const unsigned short* __restrict__ xbf,
    const unsigned short* __restrict__ wqT, const unsigned short* __restrict__ wkT,
    const unsigned short* __restrict__ wvT,
    const float* __restrict__ bq, const float* __restrict__ bk, const float* __restrict__ bv,
    unsigned short* __restrict__ Qo, unsigned short* __restrict__ Ko,
    unsigned short* __restrict__ VTo, int b0) {
  __shared__ __align__(16) char As[16384], Bs[16384];
  const int idx = blockIdx.x;
  const int xcd = idx & 7;
  const int q = idx >> 3;                   // 0..191
  const int m0 = (q & 15) << 7;             // 16 m-panels over 2048 rows
  const int zn = ((q >> 4) << 3) + xcd;     // 0..95
  const int z = zn >> 2;
  const int n0 = (zn & 3) << 7;
  const int p = z >> 3, h = z & 7;
  const unsigned short* wT = (p == 0) ? wqT : (p == 1) ? wkT : wvT;
  const float* bias = ((p == 0) ? bq : (p == 1) ? bk : bv) + (h << 9);
  const char* Ag = (const char*)xbf + ((size_t)(b0 << 10) + m0) * 1024;
  const char* Bg = (const char*)wT + (size_t)h * 524288 + (size_t)n0 * 1024;
  f32x4 acc[4][4] = {};
  gemm_core<1024, 1024, 8>(Ag, Bg, As, Bs, acc);

  const int tid = threadIdx.x, wave = tid >> 6, lane = tid & 63;
  const int wr = (wave >> 1) << 6, wc = (wave & 1) << 6;
  if (p == 2) {
#pragma unroll
    for (int j = 0; j < 4; ++j) {
      const int col = n0 + wc + (j << 4) + (lane & 15);
      const float bb = bias[col];
#pragma unroll
      for (int i = 0; i < 4; ++i) {
        const int sb = m0 + wr + (i << 4) + ((lane >> 4) << 2);   // 4 consecutive s rows
        const int lb = sb >> 10, s = sb & 1023;
        u16x4 o;
#pragma unroll
        for (int r = 0; r < 4; ++r) o[r] = f2bf(acc[i][j][r] + bb);
        *(u16x4*)(VTo + (size_t)(lb * HH + h) * 524288 +
                  (size_t)(((s >> 5) << 9) + col) * 32 + (s & 31)) = o;
      }
    }
  } else {
    unsigned short* dst = (p == 0) ? Qo : Ko;
#pragma unroll
    for (int j = 0; j < 4; ++j) {
      const int col = n0 + wc + (j << 4) + (lane & 15);
      const float bb = bias[col];
#pragma unroll
      for (int i = 0; i < 4; ++i)
#pragma unroll
        for (int r = 0; r < 4; ++r) {
          const int m = m0 + wr + (i << 4) + ((lane >> 4) << 2) + r;
          const int lb = m >> 10, s = m & 1023;
          dst[((size_t)((lb * HH + h) * SS + s) << 9) + col] = f2bf(acc[i][j][r] + bb);
        }
    }
  }
}

// ---- output projection, XCD-pinned 1-D grid 256 ---------------------------
__global__ __launch_bounds__(256, 2) void k_gemm_out(
    const unsigned short* __restrict__ concat, const unsigned short* __restrict__ woT,
    const float* __restrict__ bo, float* __restrict__ out) {
  __shared__ __align__(16) char As[16384], Bs[16384];
  const int idx = blockIdx.x;
  const int xcd = idx & 7;
  const int n0 = (xcd & 3) << 7;
  const int m0 = ((idx >> 3) + ((xcd >> 2) << 5)) << 7;
  const char* Ag = (const char*)concat + (size_t)m0 * 8192;
  const char* Bg = (const char*)woT + (size_t)n0 * 8192;
  f32x4 acc[4][4] = {};
  gemm_core<8192, 8192, 64>(Ag, Bg, As, Bs, acc);

  const int tid = threadIdx.x, wave = tid >> 6, lane = tid & 63;
  const int wr = (wave >> 1) << 6, wc = (wave & 1) << 6;
#pragma unroll
  for (int j = 0; j < 4; ++j) {
    const int col = n0 + wc + (j << 4) + (lane & 15);
    const float bb = bo[col];
#pragma unroll
    for (int i = 0; i < 4; ++i)
#pragma unroll
      for (int r = 0; r < 4; ++r) {
        const int m = m0 + wr + (i << 4) + ((lane >> 4) << 2) + r;
        out[(size_t)m * DDIM + col] = acc[i][j][r] + bb;
      }
  }
}

// ---- flash attention v11 (r16, 569us-validated): v7b + T13 defer-max ------
// Per row: keep m_old unless max grows >8 (P bounded by e^8, f32-safe).
// When ALL rows defer, fac==1 block-wide and the PV O-rescale pass is skipped
// via wave-ballot flags in LDS. (r17 in-register softmax variant: 33% SLOWER
// - serial shfl_xor chains beat by parallel Ssm round-trip; reverted.)
// LDS 145472: K dbuf 2x32KB | V dbuf 2x32KB | S [64][33] f32 | P [64x80B] |
//             m/l/f[64] | wave flags[8]
__global__ __launch_bounds__(512, 1) void k_attn(
    const unsigned short* __restrict__ Qg, const unsigned short* __restrict__ Kg,
    const unsigned short* __restrict__ VT2g, unsigned short* __restrict__ Og,
    int b0) {
  __shared__ __align__(16) char smem[145472];
  float* Ssm = (float*)(smem + 131072);      // 64*33*4 = 8448
  char*  Psm = smem + 139520;                // 64*80 = 5120
  float* msm = (float*)(smem + 144640);
  float* lsm = (float*)(smem + 144896);
  float* fsm = (float*)(smem + 145152);
  float* wfl = (float*)(smem + 145408);      // 8 per-wave rescale flags

  const int tid = threadIdx.x, wave = tid >> 6, lane = tid & 63;
  const int bh = blockIdx.x & 15;            // local bh; bh&7 = head = XCD pin
  const int qt = blockIdx.x >> 4;            // 16 qtiles of 64 rows
  const int q0 = qt << 6;
  const char* Qb = (const char*)Qg + (size_t)bh * 1048576;     // SS*DDIM*2
  const char* Kb = (const char*)Kg + (size_t)bh * 1048576;
  const char* Vb = (const char*)VT2g + (size_t)bh * 1048576;   // [32][512][32] tiled

  const int qi = wave >> 1, ni = wave & 1;   // QK^T: 4 qfrag x 2 nfrag
  const int l15 = lane & 15;
  const int kg16 = (lane >> 4) << 4;

  if (tid < 64) { msm[tid] = -1e30f; lsm[tid] = 0.0f; }

  // K tile: 32 rows x 1KB. V tile: contiguous 32KB [512 d][32 kv], swizzled.
#define STAGE_K(KV0, BUF)                                                      \
  {                                                                            \
    _Pragma("unroll")                                                          \
    for (int j = 0; j < 4; ++j) {                                              \
      const int row = (j << 3) + wave;                                         \
      gload16(Kb + (size_t)((KV0) + row) * 1024 + ((lane << 4) ^ ((row & 7) << 4)), \
              smem + (BUF) * 32768 + row * 1024);                              \
    }                                                                          \
  }
#define STAGE_V(KT, BUF)                                                       \
  {                                                                            \
    const char* vsrc = Vb + (size_t)(KT) * 32768;                              \
    _Pragma("unroll")                                                          \
    for (int j = 0; j < 4; ++j) {                                              \
      const int idx = (j << 3) + wave;                                         \
      gload16(vsrc + idx * 1024 + (size_t)((lane >> 2) << 6) +                 \
                  ((((lane & 3) ^ ((lane >> 3) & 3))) << 4),                   \
              smem + 65536 + (BUF) * 32768 + idx * 1024);                      \
    }                                                                          \
  }

  // ---- prologue: Q fragments direct to regs (one-time); stage tile 0 ----
  bf16x8 qf[16];
  {
    const char* qrow = Qb + (size_t)(q0 + (qi << 4) + l15) * 1024 + kg16;
#pragma unroll
    for (int ks = 0; ks < 16; ++ks)
      qf[ks] = *(const bf16x8*)(qrow + (ks << 6));
  }
  STAGE_K(0, 0);
  STAGE_V(0, 0);

  f32x4 accO[4][4] = {};
  const float scale = 0.044194173824159216f;   // 1/sqrt(512)

  for (int kt = 0; kt < 32; ++kt) {            // 32 tiles x kv=32 = SS=1024
    const int cur = kt & 1;
    BAR_ALL();   // staged K/V(kt) landed; all waves done reading buf[cur^1]
    if (kt != 31) {
      STAGE_K((kt + 1) << 5, cur ^ 1);   // full-iteration prefetch distance
      STAGE_V(kt + 1, cur ^ 1);
    }

    // ---- QK^T: one 16x16 S-frag per wave, 4 independent MFMA chains ----
    {
      f32x4 a0 = {}, a1 = {}, a2 = {}, a3 = {};
      const int krow = (ni << 4) + l15;
      const char* kb2 = smem + cur * 32768 + krow * 1024;
      const int ksz = (krow & 7) << 4;
      __builtin_amdgcn_s_setprio(1);
#pragma unroll
      for (int ks = 0; ks < 16; ks += 4) {
        const bf16x8 k0 = *(const bf16x8*)(kb2 + ((((ks + 0) << 6) + kg16) ^ ksz));
        const bf16x8 k1 = *(const bf16x8*)(kb2 + ((((ks + 1) << 6) + kg16) ^ ksz));
        const bf16x8 k2 = *(const bf16x8*)(kb2 + ((((ks + 2) << 6) + kg16) ^ ksz));
        const bf16x8 k3 = *(const bf16x8*)(kb2 + ((((ks + 3) << 6) + kg16) ^ ksz));
        a0 = __builtin_amdgcn_mfma_f32_16x16x32_bf16(qf[ks + 0], k0, a0, 0, 0, 0);
        a1 = __builtin_amdgcn_mfma_f32_16x16x32_bf16(qf[ks + 1], k1, a1, 0, 0, 0);
        a2 = __builtin_amdgcn_mfma_f32_16x16x32_bf16(qf[ks + 2], k2, a2, 0, 0, 0);
        a3 = __builtin_amdgcn_mfma_f32_16x16x32_bf16(qf[ks + 3], k3, a3, 0, 0, 0);
      }
      __builtin_amdgcn_s_setprio(0);
      const f32x4 s = (a0 + a1) + (a2 + a3);
      const int srow = (qi << 4) + ((lane >> 4) << 2);
      const int scol = (ni << 4) + l15;
#pragma unroll
      for (int r = 0; r < 4; ++r) Ssm[(srow + r) * 33 + scol] = s[r];
    }
    BAR_LGKM();   // S visible

    // ---- online softmax with defer-max: 64 rows x 8 lanes, 4 cols each ----
    {
      const int row = tid >> 3, c8 = tid & 7;
      float sv[4];
#pragma unroll
      for (int c = 0; c < 4; ++c) sv[c] = Ssm[row * 33 + (c8 << 2) + c] * scale;
      float mx = fmaxf(fmaxf(sv[0], sv[1]), fmaxf(sv[2], sv[3]));
      mx = fmaxf(mx, __shfl_xor(mx, 1));
      mx = fmaxf(mx, __shfl_xor(mx, 2));
      mx = fmaxf(mx, __shfl_xor(mx, 4));
      const float mold = msm[row];               // in-wave lockstep: read precedes write
      // T13 defer-max: keep m_old unless growth > 8 (P bounded by e^8)
      const float mnew = (mx - mold > 8.0f) ? mx : mold;
      const float fac = (mnew == mold) ? 1.0f : __expf(mold - mnew);
      float ls = 0.0f;
      u16x4 pv;
#pragma unroll
      for (int c = 0; c < 4; ++c) {
        const float p = __expf(sv[c] - mnew);
        ls += p;
        pv[c] = f2bf(p);
      }
      ls += __shfl_xor(ls, 1);
      ls += __shfl_xor(ls, 2);
      ls += __shfl_xor(ls, 4);
      if ((tid & 7) == 0) {
        msm[row] = mnew;
        lsm[row] = lsm[row] * fac + ls;
        fsm[row] = fac;
      }
      *(u16x4*)(Psm + row * 80 + (c8 << 3)) = pv;
      // per-wave flag: does any of this wave's 8 rows need a rescale?
      const unsigned long long need = __ballot(fac != 1.0f);
      if (lane == 0) wfl[wave] = need ? 1.0f : 0.0f;
    }
    BAR_LGKM();   // P, f, flags visible

    // ---- PV: wave owns d-slice [wave*64, +64); V from swizzled LDS tile ----
    {
      bf16x8 pf[4], vf[4];
      const int rb = (lane >> 4) << 2;
      const char* vb2 = smem + 65536 + cur * 32768;
      const int vswz = ((l15 >> 1) & 3) << 4;
#pragma unroll
      for (int i = 0; i < 4; ++i)
        pf[i] = *(const bf16x8*)(Psm + ((i << 4) + l15) * 80 + kg16);
#pragma unroll
      for (int j = 0; j < 4; ++j) {
        const int vr = (wave << 6) + (j << 4) + l15;
        vf[j] = *(const bf16x8*)(vb2 + vr * 64 + (kg16 ^ vswz));
      }
      // block-uniform rescale skip (flags are block-uniform -> no divergence)
      const float anyresc = wfl[0] + wfl[1] + wfl[2] + wfl[3] +
                            wfl[4] + wfl[5] + wfl[6] + wfl[7];
      if (anyresc != 0.0f) {
        float facs[4][4];
#pragma unroll
        for (int i = 0; i < 4; ++i)
#pragma unroll
          for (int r = 0; r < 4; ++r) facs[i][r] = fsm[(i << 4) + rb + r];
#pragma unroll
        for (int i = 0; i < 4; ++i)
#pragma unroll
          for (int j = 0; j < 4; ++j)
#pragma unroll
            for (int r = 0; r < 4; ++r) accO[i][j][r] *= facs[i][r];
      }
      __builtin_amdgcn_s_setprio(1);
#pragma unroll
      for (int i = 0; i < 4; ++i)
#pragma unroll
        for (int j = 0; j < 4; ++j)
          accO[i][j] = __builtin_amdgcn_mfma_f32_16x16x32_bf16(pf[i], vf[j], accO[i][j], 0, 0, 0);
      __builtin_amdgcn_s_setprio(0);
    }
  }

  // ---- epilogue: O /= l, write concat [b][s][h*512+d] bf16 ----
  {
    const int b = b0 + (bh >> 3), h = bh & 7;
    const int rb = (lane >> 4) << 2;
    float linv[4][4];
#pragma unroll
    for (int i = 0; i < 4; ++i)
#pragma unroll
      for (int r = 0; r < 4; ++r) linv[i][r] = 1.0f / lsm[(i << 4) + rb + r];
#pragma unroll
    for (int i = 0; i < 4; ++i)
#pragma unroll
      for (int j = 0; j < 4; ++j) {
        const int col = (wave << 6) + (j << 4) + l15;
#pragma unroll
        for (int r = 0; r < 4; ++r) {
          const int s = q0 + (i << 4) + rb + r;
          Og[((size_t)((b << 10) + s)) * HD + (h << 9) + col] = f2bf(accO[i][j][r] * linv[i][r]);
        }
      }
  }
#undef STAGE_K
#undef STAGE_V
}

// ---- host launch ---------------------------------------------------------

extern "C" void kernel_launch(void* const* d_in, const int* in_sizes, int n_in,
                              void* d_out, int out_size, void* d_ws, size_t ws_size,
                              hipStream_t stream) {
  const float* x  = (const float*)d_in[0];
  const float* Wq = (const float*)d_in[1];
  const float* bq = (const float*)d_in[2];
  const float* Wk = (const float*)d_in[3];
  const float* bk = (const float*)d_in[4];
  const float* Wv = (const float*)d_in[5];
  const float* bv = (const float*)d_in[6];
  const float* Wo = (const float*)d_in[7];
  const float* bo = (const float*)d_in[8];
  float* out = (float*)d_out;
  char* ws = (char*)d_ws;

  // Layout (top = 142.6MB, proven to fit):
  unsigned short* xbf = (unsigned short*)(ws);
  unsigned short* wqT = (unsigned short*)(ws + 8388608);
  unsigned short* wkT = (unsigned short*)(ws + 12582912);
  unsigned short* wvT = (unsigned short*)(ws + 16777216);
  unsigned short* woT = (unsigned short*)(ws + 20971520);
  unsigned short* Cw  = (unsigned short*)(ws + 25165824);
  unsigned short* Qp  = (unsigned short*)(ws + 92274688);
  unsigned short* Kp  = (unsigned short*)(ws + 92274688 + 16777216ull);
  unsigned short* VTp = (unsigned short*)(ws + 92274688 + 2 * 16777216ull);

  // 1) convert x to bf16; transpose weights to [N][K] bf16
  k_convert<<<4096, 256, 0, stream>>>(x, xbf, BS * DDIM / 4);
  k_transpose_f2b<<<dim3(8, 8, 8), 256, 0, stream>>>(Wq, wqT, 512, 512);
  k_transpose_f2b<<<dim3(8, 8, 8), 256, 0, stream>>>(Wk, wkT, 512, 512);
  k_transpose_f2b<<<dim3(8, 8, 8), 256, 0, stream>>>(Wv, wvT, 512, 512);
  k_transpose_f2b<<<dim3(64, 8, 1), 256, 0, stream>>>(Wo, woT, 4096, 512);

  // 2) 4 phases of 2 batches: QKV (XCD-pinned) -> fused attention (kv=32)
  for (int b0 = 0; b0 < BB; b0 += 2) {
    k_gemm_qkv<<<dim3(1536), 256, 0, stream>>>(xbf, wqT, wkT, wvT,
                                               bq, bk, bv, Qp, Kp, VTp, b0);
    k_attn<<<dim3(256), 512, 0, stream>>>(Qp, Kp, VTp, Cw, b0);
  }

  // 3) output projection (XCD-pinned, f32 out)
  k_gemm_out<<<dim3(256), 256, 0, stream>>>(Cw, woT, bo, out);
}